// Round 11
// baseline (68.152 us; speedup 1.0000x reference)
//
#include <hip/hip_runtime.h>

#define N_NODES 8192
#define HIDDEN 256
#define OUT_DIM 16
#define CAP 128                 // max neighbors stored; binomial max deg ~66 << 128
#define G_ROWS 16               // rows per block in the slow dense GEMM
#define PF_BLK 64               // pool blocks -> P2[64][256] = 64 KB
#define PF_N (N_NODES / PF_BLK) // 128 nodes per pool block
#define SCAN_BLK (N_NODES / 4)  // 2048 row blocks (4 rows/block, one per wave)

// ---------------- K1: wave-per-row ballot scan -> CSR + dinv ----------------
// Each wave owns one row. Slot assignment via __ballot + prefix popcount:
// deterministic, ZERO atomics (R10 lesson: even LDS atomic returns add
// un-hidden latency; cross-XCD coordination is never worth it).
// 2048+16 blocks = fully resident in one occupancy round.
__global__ void k_scan(const float* __restrict__ adj, const float* __restrict__ W1,
                       const float* __restrict__ b1, const float* __restrict__ W2,
                       int* __restrict__ cnt, int* __restrict__ nbr,
                       float* __restrict__ dinv, float* __restrict__ v,
                       int* __restrict__ flag) {
    const int t = threadIdx.x;         // 256
    const int bid = blockIdx.x;        // 2048 + 16

    if (bid >= SCAN_BLK) {             // ---- v / flag aux blocks ----
        const int bv = bid - SCAN_BLK; // 0..15
        __shared__ float sm[256];
        __shared__ int nz;
        if (t == 0) nz = 0;
        __syncthreads();
        if (bv == 0 && b1[t] != 0.0f) atomicOr(&nz, 1);
        const int kg = t >> 4, cl = t & 15;
        const int c = bv * 16 + cl;
        float partial = 0.0f;
        for (int k = kg; k < HIDDEN; k += 16)
            partial += fmaxf(W1[k], 0.0f) * W2[(size_t)k * HIDDEN + c];
        sm[t] = partial;
        __syncthreads();
        if (bv == 0 && t == 0) *flag = (nz == 0) ? 1 : 0;
        if (t < 16) {
            float acc = 0.0f;
            #pragma unroll
            for (int gg = 0; gg < 16; ++gg) acc += sm[gg * 16 + t];
            v[bv * 16 + t] = acc;
        }
        return;
    }

    // ---- row scan: one row per wave ----
    const int lane = t & 63;
    const int w = t >> 6;
    const int i = bid * 4 + w;
    const uint4* row4 = (const uint4*)(adj + (size_t)i * N_NODES);
    const unsigned long long lower = (lane == 63) ? ~0ull >> 1
                                                  : (1ull << lane) - 1ull;
    int base = 0;
    #pragma unroll 4
    for (int it = 0; it < N_NODES / 4 / 64; ++it) {   // 32 iterations
        const uint4 vv = row4[it * 64 + lane];        // wave reads 1 KB contiguous
        const int j0 = (it * 64 + lane) * 4;
        // component-wise ballot slot assignment (adj entries are 0.0f/1.0f)
        {
            const bool h = vv.x && (j0 + 0 != i);
            const unsigned long long m = __ballot(h);
            if (h) { const int p = base + __popcll(m & lower); if (p < CAP) nbr[(size_t)i * CAP + p] = j0 + 0; }
            base += __popcll(m);
        }
        {
            const bool h = vv.y && (j0 + 1 != i);
            const unsigned long long m = __ballot(h);
            if (h) { const int p = base + __popcll(m & lower); if (p < CAP) nbr[(size_t)i * CAP + p] = j0 + 1; }
            base += __popcll(m);
        }
        {
            const bool h = vv.z && (j0 + 2 != i);
            const unsigned long long m = __ballot(h);
            if (h) { const int p = base + __popcll(m & lower); if (p < CAP) nbr[(size_t)i * CAP + p] = j0 + 2; }
            base += __popcll(m);
        }
        {
            const bool h = vv.w && (j0 + 3 != i);
            const unsigned long long m = __ballot(h);
            if (h) { const int p = base + __popcll(m & lower); if (p < CAP) nbr[(size_t)i * CAP + p] = j0 + 3; }
            base += __popcll(m);
        }
    }
    if (lane == 0) {
        cnt[i] = base < CAP ? base : CAP;
        dinv[i] = rsqrtf((float)(base + 1));   // +1 self loop
    }
}

// ---------------- K2: s_i = di*(di + sum dinv_j); tt_i = di*s_i -------------
__global__ void k_srow(const int* __restrict__ cnt, const int* __restrict__ nbr,
                       const float* __restrict__ dinv,
                       float* __restrict__ s, float* __restrict__ tt) {
    const int w = threadIdx.x >> 6;
    const int lane = threadIdx.x & 63;
    const int i = blockIdx.x * 4 + w;
    const int c = cnt[i];
    const float di = dinv[i];
    float p = 0.0f;
    for (int k = lane; k < c; k += 64)
        p += dinv[nbr[(size_t)i * CAP + k]];      // pure float gather
    #pragma unroll
    for (int off = 32; off > 0; off >>= 1) p += __shfl_down(p, off);
    if (lane == 0) {
        const float si = di * (di + p);
        s[i] = si; tt[i] = di * si;
    }
}

// ---------------- K3: FAST q per node-wave | SLOW GEMM (blocks < 512) -------
__global__ void k_qg(const int* __restrict__ cnt, const int* __restrict__ nbr,
                     const float* __restrict__ dinv, const float* __restrict__ s,
                     const float* __restrict__ tt,
                     const float* __restrict__ W1, const float* __restrict__ b1,
                     const float* __restrict__ W2, const int* __restrict__ flag,
                     float* __restrict__ q, float* __restrict__ g) {
    const int t = threadIdx.x;
    if (*flag) {
        // q_i = di*(di*s_i + sum tt_j), one node per wave (2048 blocks x 4)
        const int w = t >> 6, lane = t & 63;
        const int i = blockIdx.x * 4 + w;
        const int c = cnt[i];
        const float di = dinv[i];
        float p = 0.0f;
        for (int k = lane; k < c; k += 64) p += tt[nbr[(size_t)i * CAP + k]];
        #pragma unroll
        for (int off = 32; off > 0; off >>= 1) p += __shfl_down(p, off);
        if (lane == 0) q[i] = di * (di * s[i] + p);
        return;
    }
    // SLOW: g = relu(s (x) W1 + b1) @ W2 ; s[] is complete (k_srow done)
    if (blockIdx.x >= N_NODES / G_ROWS) return;
    const int row0 = blockIdx.x * G_ROWS;
    __shared__ float hT[HIDDEN][G_ROWS];
    const float w1 = W1[t], bb = b1[t];
    for (int r = 0; r < G_ROWS; ++r)
        hT[t][r] = fmaxf(s[row0 + r] * w1 + bb, 0.0f);
    __syncthreads();
    float acc[G_ROWS];
    #pragma unroll
    for (int r = 0; r < G_ROWS; ++r) acc[r] = 0.0f;
    for (int k = 0; k < HIDDEN; ++k) {
        const float w2 = W2[(size_t)k * HIDDEN + t];
        const float4 h0 = *(const float4*)&hT[k][0];
        const float4 h1 = *(const float4*)&hT[k][4];
        const float4 h2 = *(const float4*)&hT[k][8];
        const float4 h3 = *(const float4*)&hT[k][12];
        acc[0]  += h0.x * w2;  acc[1]  += h0.y * w2;  acc[2]  += h0.z * w2;  acc[3]  += h0.w * w2;
        acc[4]  += h1.x * w2;  acc[5]  += h1.y * w2;  acc[6]  += h1.z * w2;  acc[7]  += h1.w * w2;
        acc[8]  += h2.x * w2;  acc[9]  += h2.y * w2;  acc[10] += h2.z * w2;  acc[11] += h2.w * w2;
        acc[12] += h3.x * w2;  acc[13] += h3.y * w2;  acc[14] += h3.z * w2;  acc[15] += h3.w * w2;
    }
    #pragma unroll
    for (int r = 0; r < G_ROWS; ++r)
        g[(size_t)(row0 + r) * HIDDEN + t] = acc[r];
}

// ---------------- K4: pool partials -> P2[64][256]; both paths write --------
__global__ void k_pool(const int* __restrict__ cnt, const int* __restrict__ nbr,
                       const float* __restrict__ dinv, const float* __restrict__ q,
                       const float* __restrict__ g, const float* __restrict__ v,
                       const float* __restrict__ b2, const int* __restrict__ flag,
                       float* __restrict__ P2) {
    const int t = threadIdx.x;
    const int bid = blockIdx.x;            // 64
    if (*flag) {
        const float vc = v[t], bc = b2[t];
        const int i0 = bid * PF_N;
        float pp = 0.0f;
        #pragma unroll 8
        for (int n = 0; n < PF_N; ++n)             // q load: wave-uniform, L1/L2
            pp += fmaxf(q[i0 + n] * vc + bc, 0.0f);
        P2[(size_t)bid * HIDDEN + t] = pp;
    } else {
        const float bc = b2[t];
        float pool = 0.0f;
        for (int n = 0; n < PF_N; ++n) {
            const int i = bid * PF_N + n;
            const int c = cnt[i];
            const float di = dinv[i];
            float val = di * g[(size_t)i * HIDDEN + t];
            const int* nb = nbr + (size_t)i * CAP;
            for (int k = 0; k < c; ++k) {
                const int j = nb[k];
                val += dinv[j] * g[(size_t)j * HIDDEN + t];
            }
            pool += fmaxf(di * val + bc, 0.0f);
        }
        P2[(size_t)bid * HIDDEN + t] = pool;
    }
}

// ---------------- K5: pooled = sum P2 (64 KB); out = pooled @ Wfc + bfc -----
__global__ void k_finish(const float* __restrict__ P2, const float* __restrict__ Wfc,
                         const float* __restrict__ bfc, float* __restrict__ out) {
    const int t = threadIdx.x;      // 256
    float a0 = 0.f, a1 = 0.f, a2 = 0.f, a3 = 0.f;
    #pragma unroll
    for (int r = 0; r < PF_BLK; r += 4) {
        a0 += P2[(size_t)(r + 0) * HIDDEN + t];
        a1 += P2[(size_t)(r + 1) * HIDDEN + t];
        a2 += P2[(size_t)(r + 2) * HIDDEN + t];
        a3 += P2[(size_t)(r + 3) * HIDDEN + t];
    }
    __shared__ float pooled[HIDDEN];
    pooled[t] = (a0 + a1) + (a2 + a3);
    __syncthreads();
    const int o = t & 15, kg = t >> 4;
    float pr = 0.0f;
    for (int k = kg; k < HIDDEN; k += 16) pr += pooled[k] * Wfc[k * OUT_DIM + o];
    __shared__ float red[256];
    red[t] = pr;
    __syncthreads();
    if (t < OUT_DIM) {
        float sum = bfc[t];
        #pragma unroll
        for (int gg = 0; gg < 16; ++gg) sum += red[gg * 16 + t];
        out[t] = sum;
    }
}

extern "C" void kernel_launch(void* const* d_in, const int* in_sizes, int n_in,
                              void* d_out, int out_size, void* d_ws, size_t ws_size,
                              hipStream_t stream) {
    const float* adj = (const float*)d_in[0];
    const float* W1  = (const float*)d_in[1];
    const float* b1  = (const float*)d_in[2];
    const float* W2  = (const float*)d_in[3];
    const float* b2  = (const float*)d_in[4];
    const float* Wfc = (const float*)d_in[5];
    const float* bfc = (const float*)d_in[6];
    float* out = (float*)d_out;

    // workspace layout (16 MiB used)
    char* ws = (char*)d_ws;
    int*   cnt  = (int*)  (ws + 0);                 // 32 KB
    float* s    = (float*)(ws + (32 << 10));        // 32 KB
    float* tt   = (float*)(ws + (64 << 10));        // 32 KB
    float* dinv = (float*)(ws + (96 << 10));        // 32 KB
    float* v    = (float*)(ws + (128 << 10));       // 1 KB
    int*   flag = (int*)  (ws + (132 << 10));       // 4 B
    float* q    = (float*)(ws + (136 << 10));       // 32 KB
    float* P2   = (float*)(ws + (192 << 10));       // 64 KB (64 x 256)
    int*   nbr  = (int*)  (ws + (1 << 20));         // 4 MB
    float* g    = (float*)(ws + (8 << 20));         // 8 MB (slow path only)

    k_scan  <<<SCAN_BLK + 16, 256, 0, stream>>>(adj, W1, b1, W2, cnt, nbr, dinv, v, flag);
    k_srow  <<<N_NODES / 4, 256, 0, stream>>>(cnt, nbr, dinv, s, tt);
    k_qg    <<<N_NODES / 4, 256, 0, stream>>>(cnt, nbr, dinv, s, tt, W1, b1, W2, flag, q, g);
    k_pool  <<<PF_BLK, 256, 0, stream>>>(cnt, nbr, dinv, q, g, v, b2, flag, P2);
    k_finish<<<1, 256, 0, stream>>>(P2, Wfc, bfc, out);
}

// Round 12
// 65.798 us; speedup vs baseline: 1.0358x; 1.0358x over previous
//
#include <hip/hip_runtime.h>

#define N_NODES 8192
#define HIDDEN 256
#define OUT_DIM 16
#define CAP 128                 // max neighbors stored; binomial max deg ~66 << 128
#define G_ROWS 16               // rows per block in the slow dense GEMM
#define PF_BLK 64               // pool blocks -> P2[64][256] = 64 KB
#define PF_N (N_NODES / PF_BLK) // 128 nodes per pool block

// ---------------- K1: dense row scan -> CSR + dinv; v/flag by aux blocks ----
// R10-proven: block per row, fully-unrolled 8x uint4 loads (max MLP), only
// atomic is the LDS counter. Ballot variant (R11) was slower: serial
// cross-lane chain beats no-atomic. Scan is BW-bound at ~90% of achievable.
__global__ void k_scan(const float* __restrict__ adj, const float* __restrict__ W1,
                       const float* __restrict__ b1, const float* __restrict__ W2,
                       int* __restrict__ cnt, int* __restrict__ nbr,
                       float* __restrict__ dinv, float* __restrict__ v,
                       int* __restrict__ flag) {
    const int t = threadIdx.x;         // 256
    const int bid = blockIdx.x;        // 8192 + 16

    if (bid >= N_NODES) {              // ---- v / flag blocks (16 CUs) ----
        const int bv = bid - N_NODES;  // 0..15
        __shared__ float sm[256];
        __shared__ int nz;
        if (t == 0) nz = 0;
        __syncthreads();
        if (bv == 0 && b1[t] != 0.0f) atomicOr(&nz, 1);
        const int kg = t >> 4, cl = t & 15;
        const int c = bv * 16 + cl;
        float partial = 0.0f;
        for (int k = kg; k < HIDDEN; k += 16)
            partial += fmaxf(W1[k], 0.0f) * W2[(size_t)k * HIDDEN + c];
        sm[t] = partial;
        __syncthreads();
        if (bv == 0 && t == 0) *flag = (nz == 0) ? 1 : 0;
        if (t < 16) {
            float acc = 0.0f;
            #pragma unroll
            for (int gg = 0; gg < 16; ++gg) acc += sm[gg * 16 + t];
            v[bv * 16 + t] = acc;
        }
        return;
    }

    // ---- row-builder blocks ----
    const int i = bid;
    __shared__ int scnt;
    if (t == 0) scnt = 0;
    __syncthreads();
    const uint4* row = (const uint4*)(adj + (size_t)i * N_NODES);
    #pragma unroll
    for (int c8 = 0; c8 < N_NODES / 4 / 256; ++c8) {   // 8 iterations, all loads issued early
        uint4 vv = row[c8 * 256 + t];
        int base = (c8 * 256 + t) * 4;
        if (vv.x | vv.y | vv.z | vv.w) {   // adj entries are exactly 0.0f or 1.0f
            if (vv.x && base + 0 != i) { int p = atomicAdd(&scnt, 1); if (p < CAP) nbr[(size_t)i * CAP + p] = base + 0; }
            if (vv.y && base + 1 != i) { int p = atomicAdd(&scnt, 1); if (p < CAP) nbr[(size_t)i * CAP + p] = base + 1; }
            if (vv.z && base + 2 != i) { int p = atomicAdd(&scnt, 1); if (p < CAP) nbr[(size_t)i * CAP + p] = base + 2; }
            if (vv.w && base + 3 != i) { int p = atomicAdd(&scnt, 1); if (p < CAP) nbr[(size_t)i * CAP + p] = base + 3; }
        }
    }
    __syncthreads();
    if (t == 0) {
        cnt[i] = scnt < CAP ? scnt : CAP;
        dinv[i] = rsqrtf((float)(scnt + 1));   // +1 self loop
    }
}

// ---------------- K2: s_i = di*(di + sum dinv_j); tt_i = di*s_i -------------
// Pure float gather (dinv precomputed in scan) — R11's one proven improvement.
__global__ void k_srow(const int* __restrict__ cnt, const int* __restrict__ nbr,
                       const float* __restrict__ dinv,
                       float* __restrict__ s, float* __restrict__ tt) {
    const int w = threadIdx.x >> 6;
    const int lane = threadIdx.x & 63;
    const int i = blockIdx.x * 4 + w;
    const int c = cnt[i];
    const float di = dinv[i];
    float p = 0.0f;
    for (int k = lane; k < c; k += 64)
        p += dinv[nbr[(size_t)i * CAP + k]];
    #pragma unroll
    for (int off = 32; off > 0; off >>= 1) p += __shfl_down(p, off);
    if (lane == 0) {
        const float si = di * (di + p);
        s[i] = si; tt[i] = di * si;
    }
}

// ---------------- K3: FAST q per node-wave | SLOW GEMM (blocks < 512) -------
__global__ void k_qg(const int* __restrict__ cnt, const int* __restrict__ nbr,
                     const float* __restrict__ dinv, const float* __restrict__ s,
                     const float* __restrict__ tt,
                     const float* __restrict__ W1, const float* __restrict__ b1,
                     const float* __restrict__ W2, const int* __restrict__ flag,
                     float* __restrict__ q, float* __restrict__ g) {
    const int t = threadIdx.x;
    if (*flag) {
        const int w = t >> 6, lane = t & 63;
        const int i = blockIdx.x * 4 + w;
        const int c = cnt[i];
        const float di = dinv[i];
        float p = 0.0f;
        for (int k = lane; k < c; k += 64) p += tt[nbr[(size_t)i * CAP + k]];
        #pragma unroll
        for (int off = 32; off > 0; off >>= 1) p += __shfl_down(p, off);
        if (lane == 0) q[i] = di * (di * s[i] + p);
        return;
    }
    // SLOW: g = relu(s (x) W1 + b1) @ W2 ; s[] is complete (k_srow done)
    if (blockIdx.x >= N_NODES / G_ROWS) return;
    const int row0 = blockIdx.x * G_ROWS;
    __shared__ float hT[HIDDEN][G_ROWS];
    const float w1 = W1[t], bb = b1[t];
    for (int r = 0; r < G_ROWS; ++r)
        hT[t][r] = fmaxf(s[row0 + r] * w1 + bb, 0.0f);
    __syncthreads();
    float acc[G_ROWS];
    #pragma unroll
    for (int r = 0; r < G_ROWS; ++r) acc[r] = 0.0f;
    for (int k = 0; k < HIDDEN; ++k) {
        const float w2 = W2[(size_t)k * HIDDEN + t];
        const float4 h0 = *(const float4*)&hT[k][0];
        const float4 h1 = *(const float4*)&hT[k][4];
        const float4 h2 = *(const float4*)&hT[k][8];
        const float4 h3 = *(const float4*)&hT[k][12];
        acc[0]  += h0.x * w2;  acc[1]  += h0.y * w2;  acc[2]  += h0.z * w2;  acc[3]  += h0.w * w2;
        acc[4]  += h1.x * w2;  acc[5]  += h1.y * w2;  acc[6]  += h1.z * w2;  acc[7]  += h1.w * w2;
        acc[8]  += h2.x * w2;  acc[9]  += h2.y * w2;  acc[10] += h2.z * w2;  acc[11] += h2.w * w2;
        acc[12] += h3.x * w2;  acc[13] += h3.y * w2;  acc[14] += h3.z * w2;  acc[15] += h3.w * w2;
    }
    #pragma unroll
    for (int r = 0; r < G_ROWS; ++r)
        g[(size_t)(row0 + r) * HIDDEN + t] = acc[r];
}

// ---------------- K4: pool partials -> P2[64][256]; both paths write --------
__global__ void k_pool(const int* __restrict__ cnt, const int* __restrict__ nbr,
                       const float* __restrict__ dinv, const float* __restrict__ q,
                       const float* __restrict__ g, const float* __restrict__ v,
                       const float* __restrict__ b2, const int* __restrict__ flag,
                       float* __restrict__ P2) {
    const int t = threadIdx.x;
    const int bid = blockIdx.x;            // 64
    if (*flag) {
        const float vc = v[t], bc = b2[t];
        const int i0 = bid * PF_N;
        float pp = 0.0f;
        #pragma unroll 8
        for (int n = 0; n < PF_N; ++n)             // q load: wave-uniform, L1/L2
            pp += fmaxf(q[i0 + n] * vc + bc, 0.0f);
        P2[(size_t)bid * HIDDEN + t] = pp;
    } else {
        const float bc = b2[t];
        float pool = 0.0f;
        for (int n = 0; n < PF_N; ++n) {
            const int i = bid * PF_N + n;
            const int c = cnt[i];
            const float di = dinv[i];
            float val = di * g[(size_t)i * HIDDEN + t];
            const int* nb = nbr + (size_t)i * CAP;
            for (int k = 0; k < c; ++k) {
                const int j = nb[k];
                val += dinv[j] * g[(size_t)j * HIDDEN + t];
            }
            pool += fmaxf(di * val + bc, 0.0f);
        }
        P2[(size_t)bid * HIDDEN + t] = pool;
    }
}

// ---------------- K5: pooled = sum P2 (64 KB); out = pooled @ Wfc + bfc -----
__global__ void k_finish(const float* __restrict__ P2, const float* __restrict__ Wfc,
                         const float* __restrict__ bfc, float* __restrict__ out) {
    const int t = threadIdx.x;      // 256
    float a0 = 0.f, a1 = 0.f, a2 = 0.f, a3 = 0.f;
    #pragma unroll
    for (int r = 0; r < PF_BLK; r += 4) {
        a0 += P2[(size_t)(r + 0) * HIDDEN + t];
        a1 += P2[(size_t)(r + 1) * HIDDEN + t];
        a2 += P2[(size_t)(r + 2) * HIDDEN + t];
        a3 += P2[(size_t)(r + 3) * HIDDEN + t];
    }
    __shared__ float pooled[HIDDEN];
    pooled[t] = (a0 + a1) + (a2 + a3);
    __syncthreads();
    const int o = t & 15, kg = t >> 4;
    float pr = 0.0f;
    for (int k = kg; k < HIDDEN; k += 16) pr += pooled[k] * Wfc[k * OUT_DIM + o];
    __shared__ float red[256];
    red[t] = pr;
    __syncthreads();
    if (t < OUT_DIM) {
        float sum = bfc[t];
        #pragma unroll
        for (int gg = 0; gg < 16; ++gg) sum += red[gg * 16 + t];
        out[t] = sum;
    }
}

extern "C" void kernel_launch(void* const* d_in, const int* in_sizes, int n_in,
                              void* d_out, int out_size, void* d_ws, size_t ws_size,
                              hipStream_t stream) {
    const float* adj = (const float*)d_in[0];
    const float* W1  = (const float*)d_in[1];
    const float* b1  = (const float*)d_in[2];
    const float* W2  = (const float*)d_in[3];
    const float* b2  = (const float*)d_in[4];
    const float* Wfc = (const float*)d_in[5];
    const float* bfc = (const float*)d_in[6];
    float* out = (float*)d_out;

    // workspace layout (16 MiB used)
    char* ws = (char*)d_ws;
    int*   cnt  = (int*)  (ws + 0);                 // 32 KB
    float* s    = (float*)(ws + (32 << 10));        // 32 KB
    float* tt   = (float*)(ws + (64 << 10));        // 32 KB
    float* dinv = (float*)(ws + (96 << 10));        // 32 KB
    float* v    = (float*)(ws + (128 << 10));       // 1 KB
    int*   flag = (int*)  (ws + (132 << 10));       // 4 B
    float* q    = (float*)(ws + (136 << 10));       // 32 KB
    float* P2   = (float*)(ws + (192 << 10));       // 64 KB (64 x 256)
    int*   nbr  = (int*)  (ws + (1 << 20));         // 4 MB
    float* g    = (float*)(ws + (8 << 20));         // 8 MB (slow path only)

    k_scan  <<<N_NODES + 16, 256, 0, stream>>>(adj, W1, b1, W2, cnt, nbr, dinv, v, flag);
    k_srow  <<<N_NODES / 4, 256, 0, stream>>>(cnt, nbr, dinv, s, tt);
    k_qg    <<<N_NODES / 4, 256, 0, stream>>>(cnt, nbr, dinv, s, tt, W1, b1, W2, flag, q, g);
    k_pool  <<<PF_BLK, 256, 0, stream>>>(cnt, nbr, dinv, q, g, v, b2, flag, P2);
    k_finish<<<1, 256, 0, stream>>>(P2, Wfc, bfc, out);
}

// Round 13
// 65.290 us; speedup vs baseline: 1.0438x; 1.0078x over previous
//
#include <hip/hip_runtime.h>

#define N_NODES 8192
#define HIDDEN 256
#define OUT_DIM 16
#define CAP 128                 // max neighbors stored; binomial max deg ~66 << 128
#define G_ROWS 16               // rows per block in the slow dense GEMM
#define PF_BLK 64               // pool blocks -> P2[64][256] = 64 KB
#define PF_N (N_NODES / PF_BLK) // 128 nodes per pool block

// ---------------- K1: dense row scan -> CSR + dinv; v/flag by aux blocks ----
// R12 base, single change: 32 B/thread/iter (2 x uint4, contiguous), 4 iters.
// Tests whether the scan is outstanding-load-limited rather than BW-limited
// (R8's FETCH=132MB says HBM delivers only ~2.6 TB/s during the scan).
__global__ void k_scan(const float* __restrict__ adj, const float* __restrict__ W1,
                       const float* __restrict__ b1, const float* __restrict__ W2,
                       int* __restrict__ cnt, int* __restrict__ nbr,
                       float* __restrict__ dinv, float* __restrict__ v,
                       int* __restrict__ flag) {
    const int t = threadIdx.x;         // 256
    const int bid = blockIdx.x;        // 8192 + 16

    if (bid >= N_NODES) {              // ---- v / flag blocks (16 CUs) ----
        const int bv = bid - N_NODES;  // 0..15
        __shared__ float sm[256];
        __shared__ int nz;
        if (t == 0) nz = 0;
        __syncthreads();
        if (bv == 0 && b1[t] != 0.0f) atomicOr(&nz, 1);
        const int kg = t >> 4, cl = t & 15;
        const int c = bv * 16 + cl;
        float partial = 0.0f;
        for (int k = kg; k < HIDDEN; k += 16)
            partial += fmaxf(W1[k], 0.0f) * W2[(size_t)k * HIDDEN + c];
        sm[t] = partial;
        __syncthreads();
        if (bv == 0 && t == 0) *flag = (nz == 0) ? 1 : 0;
        if (t < 16) {
            float acc = 0.0f;
            #pragma unroll
            for (int gg = 0; gg < 16; ++gg) acc += sm[gg * 16 + t];
            v[bv * 16 + t] = acc;
        }
        return;
    }

    // ---- row-builder blocks: 2 x uint4 per thread per iteration ----
    const int i = bid;
    __shared__ int scnt;
    if (t == 0) scnt = 0;
    __syncthreads();
    const uint4* row = (const uint4*)(adj + (size_t)i * N_NODES);
    #pragma unroll
    for (int c8 = 0; c8 < N_NODES / 4 / 512; ++c8) {   // 4 iterations
        const int idx = c8 * 512 + 2 * t;
        const uint4 va = row[idx];
        const uint4 vb = row[idx + 1];
        const int ba = idx * 4;
        if (va.x | va.y | va.z | va.w) {
            if (va.x && ba + 0 != i) { int p = atomicAdd(&scnt, 1); if (p < CAP) nbr[(size_t)i * CAP + p] = ba + 0; }
            if (va.y && ba + 1 != i) { int p = atomicAdd(&scnt, 1); if (p < CAP) nbr[(size_t)i * CAP + p] = ba + 1; }
            if (va.z && ba + 2 != i) { int p = atomicAdd(&scnt, 1); if (p < CAP) nbr[(size_t)i * CAP + p] = ba + 2; }
            if (va.w && ba + 3 != i) { int p = atomicAdd(&scnt, 1); if (p < CAP) nbr[(size_t)i * CAP + p] = ba + 3; }
        }
        if (vb.x | vb.y | vb.z | vb.w) {
            if (vb.x && ba + 4 != i) { int p = atomicAdd(&scnt, 1); if (p < CAP) nbr[(size_t)i * CAP + p] = ba + 4; }
            if (vb.y && ba + 5 != i) { int p = atomicAdd(&scnt, 1); if (p < CAP) nbr[(size_t)i * CAP + p] = ba + 5; }
            if (vb.z && ba + 6 != i) { int p = atomicAdd(&scnt, 1); if (p < CAP) nbr[(size_t)i * CAP + p] = ba + 6; }
            if (vb.w && ba + 7 != i) { int p = atomicAdd(&scnt, 1); if (p < CAP) nbr[(size_t)i * CAP + p] = ba + 7; }
        }
    }
    __syncthreads();
    if (t == 0) {
        cnt[i] = scnt < CAP ? scnt : CAP;
        dinv[i] = rsqrtf((float)(scnt + 1));   // +1 self loop
    }
}

// ---------------- K2: s_i = di*(di + sum dinv_j); tt_i = di*s_i -------------
__global__ void k_srow(const int* __restrict__ cnt, const int* __restrict__ nbr,
                       const float* __restrict__ dinv,
                       float* __restrict__ s, float* __restrict__ tt) {
    const int w = threadIdx.x >> 6;
    const int lane = threadIdx.x & 63;
    const int i = blockIdx.x * 4 + w;
    const int c = cnt[i];
    const float di = dinv[i];
    float p = 0.0f;
    for (int k = lane; k < c; k += 64)
        p += dinv[nbr[(size_t)i * CAP + k]];
    #pragma unroll
    for (int off = 32; off > 0; off >>= 1) p += __shfl_down(p, off);
    if (lane == 0) {
        const float si = di * (di + p);
        s[i] = si; tt[i] = di * si;
    }
}

// ---------------- K3: FAST q per node-wave | SLOW GEMM (blocks < 512) -------
__global__ void k_qg(const int* __restrict__ cnt, const int* __restrict__ nbr,
                     const float* __restrict__ dinv, const float* __restrict__ s,
                     const float* __restrict__ tt,
                     const float* __restrict__ W1, const float* __restrict__ b1,
                     const float* __restrict__ W2, const int* __restrict__ flag,
                     float* __restrict__ q, float* __restrict__ g) {
    const int t = threadIdx.x;
    if (*flag) {
        const int w = t >> 6, lane = t & 63;
        const int i = blockIdx.x * 4 + w;
        const int c = cnt[i];
        const float di = dinv[i];
        float p = 0.0f;
        for (int k = lane; k < c; k += 64) p += tt[nbr[(size_t)i * CAP + k]];
        #pragma unroll
        for (int off = 32; off > 0; off >>= 1) p += __shfl_down(p, off);
        if (lane == 0) q[i] = di * (di * s[i] + p);
        return;
    }
    // SLOW: g = relu(s (x) W1 + b1) @ W2 ; s[] is complete (k_srow done)
    if (blockIdx.x >= N_NODES / G_ROWS) return;
    const int row0 = blockIdx.x * G_ROWS;
    __shared__ float hT[HIDDEN][G_ROWS];
    const float w1 = W1[t], bb = b1[t];
    for (int r = 0; r < G_ROWS; ++r)
        hT[t][r] = fmaxf(s[row0 + r] * w1 + bb, 0.0f);
    __syncthreads();
    float acc[G_ROWS];
    #pragma unroll
    for (int r = 0; r < G_ROWS; ++r) acc[r] = 0.0f;
    for (int k = 0; k < HIDDEN; ++k) {
        const float w2 = W2[(size_t)k * HIDDEN + t];
        const float4 h0 = *(const float4*)&hT[k][0];
        const float4 h1 = *(const float4*)&hT[k][4];
        const float4 h2 = *(const float4*)&hT[k][8];
        const float4 h3 = *(const float4*)&hT[k][12];
        acc[0]  += h0.x * w2;  acc[1]  += h0.y * w2;  acc[2]  += h0.z * w2;  acc[3]  += h0.w * w2;
        acc[4]  += h1.x * w2;  acc[5]  += h1.y * w2;  acc[6]  += h1.z * w2;  acc[7]  += h1.w * w2;
        acc[8]  += h2.x * w2;  acc[9]  += h2.y * w2;  acc[10] += h2.z * w2;  acc[11] += h2.w * w2;
        acc[12] += h3.x * w2;  acc[13] += h3.y * w2;  acc[14] += h3.z * w2;  acc[15] += h3.w * w2;
    }
    #pragma unroll
    for (int r = 0; r < G_ROWS; ++r)
        g[(size_t)(row0 + r) * HIDDEN + t] = acc[r];
}

// ---------------- K4: pool partials -> P2[64][256]; both paths write --------
__global__ void k_pool(const int* __restrict__ cnt, const int* __restrict__ nbr,
                       const float* __restrict__ dinv, const float* __restrict__ q,
                       const float* __restrict__ g, const float* __restrict__ v,
                       const float* __restrict__ b2, const int* __restrict__ flag,
                       float* __restrict__ P2) {
    const int t = threadIdx.x;
    const int bid = blockIdx.x;            // 64
    if (*flag) {
        const float vc = v[t], bc = b2[t];
        const int i0 = bid * PF_N;
        float pp = 0.0f;
        #pragma unroll 8
        for (int n = 0; n < PF_N; ++n)             // q load: wave-uniform, L1/L2
            pp += fmaxf(q[i0 + n] * vc + bc, 0.0f);
        P2[(size_t)bid * HIDDEN + t] = pp;
    } else {
        const float bc = b2[t];
        float pool = 0.0f;
        for (int n = 0; n < PF_N; ++n) {
            const int i = bid * PF_N + n;
            const int c = cnt[i];
            const float di = dinv[i];
            float val = di * g[(size_t)i * HIDDEN + t];
            const int* nb = nbr + (size_t)i * CAP;
            for (int k = 0; k < c; ++k) {
                const int j = nb[k];
                val += dinv[j] * g[(size_t)j * HIDDEN + t];
            }
            pool += fmaxf(di * val + bc, 0.0f);
        }
        P2[(size_t)bid * HIDDEN + t] = pool;
    }
}

// ---------------- K5: pooled = sum P2 (64 KB); out = pooled @ Wfc + bfc -----
__global__ void k_finish(const float* __restrict__ P2, const float* __restrict__ Wfc,
                         const float* __restrict__ bfc, float* __restrict__ out) {
    const int t = threadIdx.x;      // 256
    float a0 = 0.f, a1 = 0.f, a2 = 0.f, a3 = 0.f;
    #pragma unroll
    for (int r = 0; r < PF_BLK; r += 4) {
        a0 += P2[(size_t)(r + 0) * HIDDEN + t];
        a1 += P2[(size_t)(r + 1) * HIDDEN + t];
        a2 += P2[(size_t)(r + 2) * HIDDEN + t];
        a3 += P2[(size_t)(r + 3) * HIDDEN + t];
    }
    __shared__ float pooled[HIDDEN];
    pooled[t] = (a0 + a1) + (a2 + a3);
    __syncthreads();
    const int o = t & 15, kg = t >> 4;
    float pr = 0.0f;
    for (int k = kg; k < HIDDEN; k += 16) pr += pooled[k] * Wfc[k * OUT_DIM + o];
    __shared__ float red[256];
    red[t] = pr;
    __syncthreads();
    if (t < OUT_DIM) {
        float sum = bfc[t];
        #pragma unroll
        for (int gg = 0; gg < 16; ++gg) sum += red[gg * 16 + t];
        out[t] = sum;
    }
}

extern "C" void kernel_launch(void* const* d_in, const int* in_sizes, int n_in,
                              void* d_out, int out_size, void* d_ws, size_t ws_size,
                              hipStream_t stream) {
    const float* adj = (const float*)d_in[0];
    const float* W1  = (const float*)d_in[1];
    const float* b1  = (const float*)d_in[2];
    const float* W2  = (const float*)d_in[3];
    const float* b2  = (const float*)d_in[4];
    const float* Wfc = (const float*)d_in[5];
    const float* bfc = (const float*)d_in[6];
    float* out = (float*)d_out;

    // workspace layout (16 MiB used)
    char* ws = (char*)d_ws;
    int*   cnt  = (int*)  (ws + 0);                 // 32 KB
    float* s    = (float*)(ws + (32 << 10));        // 32 KB
    float* tt   = (float*)(ws + (64 << 10));        // 32 KB
    float* dinv = (float*)(ws + (96 << 10));        // 32 KB
    float* v    = (float*)(ws + (128 << 10));       // 1 KB
    int*   flag = (int*)  (ws + (132 << 10));       // 4 B
    float* q    = (float*)(ws + (136 << 10));       // 32 KB
    float* P2   = (float*)(ws + (192 << 10));       // 64 KB (64 x 256)
    int*   nbr  = (int*)  (ws + (1 << 20));         // 4 MB
    float* g    = (float*)(ws + (8 << 20));         // 8 MB (slow path only)

    k_scan  <<<N_NODES + 16, 256, 0, stream>>>(adj, W1, b1, W2, cnt, nbr, dinv, v, flag);
    k_srow  <<<N_NODES / 4, 256, 0, stream>>>(cnt, nbr, dinv, s, tt);
    k_qg    <<<N_NODES / 4, 256, 0, stream>>>(cnt, nbr, dinv, s, tt, W1, b1, W2, flag, q, g);
    k_pool  <<<PF_BLK, 256, 0, stream>>>(cnt, nbr, dinv, q, g, v, b2, flag, P2);
    k_finish<<<1, 256, 0, stream>>>(P2, Wfc, bfc, out);
}